// Round 1
// baseline (119.171 us; speedup 1.0000x reference)
//
#include <hip/hip_runtime.h>

// TensorSnake step: G games, 32x32 board, fp32 state in {-1,0,1..len}.
// One block (256 threads) per game; each thread owns 4 contiguous cells
// (one float4). Board lives in registers; block-scan via shfl + tiny LDS.

constexpr int S = 32;
constexpr int CELLS = S * S;   // 1024
constexpr int CH = S / 2;      // 16

__global__ __launch_bounds__(256) void snake_kernel(
    const float* __restrict__ state,
    const int*   __restrict__ pos_prev,
    const int*   __restrict__ pos_cur,
    const int*   __restrict__ action,
    const float* __restrict__ rand_u,
    float*       __restrict__ out)
{
    const int g   = blockIdx.x;
    const int tid = threadIdx.x;
    const size_t gbase = (size_t)g * CELLS;

    // ---- scalar per-game head logic (redundant across threads; uniform) ----
    const int ppx = pos_prev[2*g],   ppy = pos_prev[2*g+1];
    const int pcx = pos_cur[2*g],    pcy = pos_cur[2*g+1];
    const int act = action[g];
    const float ru = rand_u[g];

    int dx = pcx - ppx, dy = pcy - ppy;
    int ndx, ndy;
    if (act == 0)      { ndx = -dy; ndy =  dx; }   // left
    else if (act == 2) { ndx =  dy; ndy = -dx; }   // right
    else               { ndx =  dx; ndy =  dy; }   // straight
    int pnx = pcx + ndx, pny = pcy + ndy;
    const bool outside = (pnx < 0) || (pnx >= S) || (pny < 0) || (pny >= S);
    pnx = min(max(pnx, 0), S - 1);
    pny = min(max(pny, 0), S - 1);
    const float cell = state[gbase + pnx * S + pny];   // old state, clipped pn
    const bool dead    = outside || (cell > 0.0f);
    const bool feeding = (cell == -1.0f);
    const bool spawn   = dead || feeding;

    const int pn_idx = dead ? (CH*S + CH)     : (pnx * S + pny);
    const int pc_idx = dead ? (CH*S + CH - 1) : (pcx * S + pcy);

    // ---- effective board: reset pattern if dead, else loaded state ----
    const int base = tid * 4;
    float vals[4];
    if (!dead) {
        const float4 v = reinterpret_cast<const float4*>(state + gbase)[tid];
        vals[0] = v.x; vals[1] = v.y; vals[2] = v.z; vals[3] = v.w;
    } else {
        #pragma unroll
        for (int c = 0; c < 4; ++c) {
            const int j = base + c;
            vals[c] = (j == CH*S + CH - 1) ? 2.0f
                    : ((j == CH*S + CH - 2) || (j == CH*S + CH)) ? 1.0f
                    : 0.0f;
        }
    }

    // ---- free-cell count + block inclusive scan ----
    int cnt = 0;
    #pragma unroll
    for (int c = 0; c < 4; ++c) cnt += (vals[c] == 0.0f) ? 1 : 0;

    const int lane = tid & 63;
    const int wave = tid >> 6;
    int incl = cnt;
    #pragma unroll
    for (int off = 1; off < 64; off <<= 1) {
        int n = __shfl_up(incl, off, 64);
        if (lane >= off) incl += n;
    }

    __shared__ int   wave_sums[4];
    __shared__ int   food_s;
    __shared__ float vcur_s;
    if (lane == 63) wave_sums[wave] = incl;
    if (tid == 0)   food_s = CELLS;                 // sentinel: no owner
    if (tid == (pc_idx >> 2)) vcur_s = vals[pc_idx & 3];
    __syncthreads();

    int offset = 0;
    #pragma unroll
    for (int w = 0; w < 3; ++w) if (w < wave) offset += wave_sums[w];
    const int total = wave_sums[0] + wave_sums[1] + wave_sums[2] + wave_sums[3];
    const int excl  = offset + incl - cnt;

    // food = #{j : cdf[j] <= ru*total}  == index of (K+1)-th free cell,
    // K = floor(thresh). Exact: cdf integer-valued, thresh fp32 as in ref.
    const float thresh = ru * (float)total;
    const int target = (int)thresh + 1;             // K+1, thresh >= 0
    if (excl < target && target <= excl + cnt) {
        int acc = 0, loc = 0;
        const int r = target - excl;                // 1..4
        #pragma unroll
        for (int c = 0; c < 4; ++c) {
            acc += (vals[c] == 0.0f) ? 1 : 0;
            if (acc == r) { loc = c; acc = -1000; } // latch first match
        }
        food_s = base + loc;                        // single writer
    }
    __syncthreads();
    const int food = min(food_s, CELLS - 1);

    // ---- head value: post-food, post-dec value at pos_cur, +1 ----
    float vc = vcur_s;
    if (spawn && pc_idx == food) vc = -1.0f;
    if (vc > 0.0f && !feeding) vc -= 1.0f;
    const float head_val = vc + 1.0f;

    // ---- per-cell output: food set -> decrement -> head write ----
    #pragma unroll
    for (int c = 0; c < 4; ++c) {
        const int j = base + c;
        float val = vals[c];
        if (spawn && j == food) val = -1.0f;
        if (val > 0.0f && !feeding) val -= 1.0f;
        if (j == pn_idx) val = head_val;
        vals[c] = val;
    }
    float4 o; o.x = vals[0]; o.y = vals[1]; o.z = vals[2]; o.w = vals[3];
    reinterpret_cast<float4*>(out + gbase)[tid] = o;
}

extern "C" void kernel_launch(void* const* d_in, const int* in_sizes, int n_in,
                              void* d_out, int out_size, void* d_ws, size_t ws_size,
                              hipStream_t stream) {
    const float* state    = (const float*)d_in[0];
    const int*   pos_prev = (const int*)  d_in[1];
    const int*   pos_cur  = (const int*)  d_in[2];
    const int*   action   = (const int*)  d_in[3];
    const float* rand_u   = (const float*)d_in[4];
    float* outp = (float*)d_out;
    const int G = in_sizes[3];   // action has one entry per game
    snake_kernel<<<G, 256, 0, stream>>>(state, pos_prev, pos_cur, action, rand_u, outp);
}

// Round 2
// 116.373 us; speedup vs baseline: 1.0240x; 1.0240x over previous
//
#include <hip/hip_runtime.h>

// TensorSnake step: G games, 32x32 board, fp32 state in {-1,0,1..len}.
// One WAVE (64 lanes) per game, 4 games per 256-thread block.
// Each lane owns 16 contiguous cells (4x float4). No LDS, no barriers:
// free-cell scan via shfl_up, food/head broadcasts via ballot/shfl.

constexpr int S = 32;
constexpr int CELLS = S * S;   // 1024
constexpr int CH = S / 2;      // 16
constexpr int GPB = 4;         // games (waves) per block

__global__ __launch_bounds__(256) void snake_kernel(
    const float* __restrict__ state,
    const int*   __restrict__ pos_prev,
    const int*   __restrict__ pos_cur,
    const int*   __restrict__ action,
    const float* __restrict__ rand_u,
    float*       __restrict__ out)
{
    const int lane = threadIdx.x & 63;
    const int g    = blockIdx.x * GPB + (threadIdx.x >> 6);
    const size_t gbase = (size_t)g * CELLS;

    // ---- issue bulk state load FIRST, unconditionally (4 independent f4s) ----
    const float4* sp = reinterpret_cast<const float4*>(state + gbase);
    float4 v0 = sp[lane * 4 + 0];
    float4 v1 = sp[lane * 4 + 1];
    float4 v2 = sp[lane * 4 + 2];
    float4 v3 = sp[lane * 4 + 3];

    // ---- per-game scalars (wave-uniform values) ----
    const int ppx = pos_prev[2*g],   ppy = pos_prev[2*g+1];
    const int pcx = pos_cur[2*g],    pcy = pos_cur[2*g+1];
    const int act = action[g];
    const float ru = rand_u[g];

    int dx = pcx - ppx, dy = pcy - ppy;
    int ndx, ndy;
    if (act == 0)      { ndx = -dy; ndy =  dx; }   // left
    else if (act == 2) { ndx =  dy; ndy = -dx; }   // right
    else               { ndx =  dx; ndy =  dy; }   // straight
    int pnx = pcx + ndx, pny = pcy + ndy;
    const bool outside = (pnx < 0) || (pnx >= S) || (pny < 0) || (pny >= S);
    pnx = min(max(pnx, 0), S - 1);
    pny = min(max(pny, 0), S - 1);
    const float cell = state[gbase + pnx * S + pny];   // old state, clipped pn
    const bool dead    = outside || (cell > 0.0f);
    const bool feeding = (cell == -1.0f);
    const bool spawn   = dead || feeding;

    const int pn_idx = dead ? (CH*S + CH)     : (pnx * S + pny);
    const int pc_idx = dead ? (CH*S + CH - 1) : (pcx * S + pcy);

    // ---- effective board in registers ----
    const int base = lane * 16;
    float vals[16];
    vals[0]=v0.x; vals[1]=v0.y; vals[2]=v0.z; vals[3]=v0.w;
    vals[4]=v1.x; vals[5]=v1.y; vals[6]=v1.z; vals[7]=v1.w;
    vals[8]=v2.x; vals[9]=v2.y; vals[10]=v2.z; vals[11]=v2.w;
    vals[12]=v3.x; vals[13]=v3.y; vals[14]=v3.z; vals[15]=v3.w;
    if (dead) {   // wave-uniform branch
        #pragma unroll
        for (int c = 0; c < 16; ++c) {
            const int j = base + c;
            vals[c] = (j == CH*S + CH - 1) ? 2.0f
                    : ((j == CH*S + CH - 2) || (j == CH*S + CH)) ? 1.0f
                    : 0.0f;
        }
    }

    // ---- free-cell count + wave inclusive scan (cells in flat order) ----
    int cnt = 0;
    #pragma unroll
    for (int c = 0; c < 16; ++c) cnt += (vals[c] == 0.0f) ? 1 : 0;

    int incl = cnt;
    #pragma unroll
    for (int off = 1; off < 64; off <<= 1) {
        int n = __shfl_up(incl, off, 64);
        if (lane >= off) incl += n;
    }
    const int total = __shfl(incl, 63, 64);
    const int excl  = incl - cnt;

    // food = #{j : cdf[j] <= ru*total} == index of (K+1)-th free cell,
    // K = floor(thresh); exact since cdf integer-valued, thresh fp32 as ref.
    const float thresh = ru * (float)total;
    const int target = (int)thresh + 1;
    const bool owns = (excl < target) && (target <= incl);
    int foodloc = CELLS - 1;          // default when no owner (K >= total)
    if (owns) {
        int acc = 0, loc = 0;
        const int r = target - excl;  // 1..16
        #pragma unroll
        for (int c = 0; c < 16; ++c) {
            acc += (vals[c] == 0.0f) ? 1 : 0;
            if (acc == r) { loc = c; acc = -1000; }   // latch first match
        }
        foodloc = base + loc;
    }
    const unsigned long long omask = __ballot(owns);
    int food = CELLS - 1;
    if (omask) {
        const int ol = __ffsll(omask) - 1;
        food = __shfl(foodloc, ol, 64);
    }

    // ---- head value: post-food, post-dec value at pos_cur, +1 ----
    const int sel = pc_idx & 15;
    float cand = 0.0f;
    #pragma unroll
    for (int c = 0; c < 16; ++c) if (sel == c) cand = vals[c];
    float vc = __shfl(cand, pc_idx >> 4, 64);
    if (spawn && pc_idx == food) vc = -1.0f;
    if (vc > 0.0f && !feeding) vc -= 1.0f;
    const float head_val = vc + 1.0f;

    // ---- per-cell output: food set -> decrement -> head write ----
    #pragma unroll
    for (int c = 0; c < 16; ++c) {
        const int j = base + c;
        float val = vals[c];
        if (spawn && j == food) val = -1.0f;
        if (val > 0.0f && !feeding) val -= 1.0f;
        if (j == pn_idx) val = head_val;
        vals[c] = val;
    }
    float4* op = reinterpret_cast<float4*>(out + gbase);
    float4 o0 = make_float4(vals[0],  vals[1],  vals[2],  vals[3]);
    float4 o1 = make_float4(vals[4],  vals[5],  vals[6],  vals[7]);
    float4 o2 = make_float4(vals[8],  vals[9],  vals[10], vals[11]);
    float4 o3 = make_float4(vals[12], vals[13], vals[14], vals[15]);
    op[lane * 4 + 0] = o0;
    op[lane * 4 + 1] = o1;
    op[lane * 4 + 2] = o2;
    op[lane * 4 + 3] = o3;
}

extern "C" void kernel_launch(void* const* d_in, const int* in_sizes, int n_in,
                              void* d_out, int out_size, void* d_ws, size_t ws_size,
                              hipStream_t stream) {
    const float* state    = (const float*)d_in[0];
    const int*   pos_prev = (const int*)  d_in[1];
    const int*   pos_cur  = (const int*)  d_in[2];
    const int*   action   = (const int*)  d_in[3];
    const float* rand_u   = (const float*)d_in[4];
    float* outp = (float*)d_out;
    const int G = in_sizes[3];   // action has one entry per game
    snake_kernel<<<G / GPB, 256, 0, stream>>>(state, pos_prev, pos_cur, action, rand_u, outp);
}

// Round 3
// 98.943 us; speedup vs baseline: 1.2044x; 1.1762x over previous
//
#include <hip/hip_runtime.h>

// TensorSnake step: G games, 32x32 board, fp32 state in {-1,0,1..len}.
// One WAVE (64 lanes) per game, 4 games per 256-thread block.
// INTERLEAVED ownership: lane i owns cells j = k*256 + 4i + c (k,c in 0..3),
// so each float4 load/store instruction is a contiguous 1KB segment (perfect
// coalescing). Flat-order free-cell scan via ONE u64 shfl_up scan with four
// packed 16-bit per-quarter counts. No LDS, no barriers, no global gather.

constexpr int S = 32;
constexpr int CELLS = S * S;   // 1024
constexpr int CH = S / 2;      // 16
constexpr int GPB = 4;         // games (waves) per block

__global__ __launch_bounds__(256) void snake_kernel(
    const float* __restrict__ state,
    const int*   __restrict__ pos_prev,
    const int*   __restrict__ pos_cur,
    const int*   __restrict__ action,
    const float* __restrict__ rand_u,
    float*       __restrict__ out)
{
    const int lane = threadIdx.x & 63;
    const int g    = blockIdx.x * GPB + (threadIdx.x >> 6);
    const size_t gbase = (size_t)g * CELLS;

    // ---- coalesced bulk load: 4 instructions, each a contiguous 1KB ----
    const float4* sp = reinterpret_cast<const float4*>(state + gbase);
    const float4 v0 = sp[lane];
    const float4 v1 = sp[lane + 64];
    const float4 v2 = sp[lane + 128];
    const float4 v3 = sp[lane + 192];

    // ---- per-game scalars (wave-uniform values) ----
    const int ppx = pos_prev[2*g],   ppy = pos_prev[2*g+1];
    const int pcx = pos_cur[2*g],    pcy = pos_cur[2*g+1];
    const int act = action[g];
    const float ru = rand_u[g];

    int dx = pcx - ppx, dy = pcy - ppy;
    int ndx, ndy;
    if (act == 0)      { ndx = -dy; ndy =  dx; }   // left
    else if (act == 2) { ndx =  dy; ndy = -dx; }   // right
    else               { ndx =  dx; ndy =  dy; }   // straight
    int pnx = pcx + ndx, pny = pcy + ndy;
    const bool outside = (pnx < 0) || (pnx >= S) || (pny < 0) || (pny >= S);
    pnx = min(max(pnx, 0), S - 1);
    pny = min(max(pny, 0), S - 1);
    const int pn_raw = pnx * S + pny;   // clipped pn, flat index (uniform)

    // ---- board in registers; slot s = k*4+c holds cell j = k*256+4*lane+c ----
    float vals[16];
    vals[0]=v0.x; vals[1]=v0.y; vals[2]=v0.z; vals[3]=v0.w;
    vals[4]=v1.x; vals[5]=v1.y; vals[6]=v1.z; vals[7]=v1.w;
    vals[8]=v2.x; vals[9]=v2.y; vals[10]=v2.z; vals[11]=v2.w;
    vals[12]=v3.x; vals[13]=v3.y; vals[14]=v3.z; vals[15]=v3.w;

    // ---- head-cell probe from registers (no global gather) ----
    const int cell_slot = ((pn_raw >> 8) << 2) | (pn_raw & 3);   // uniform
    const int cell_lane = (pn_raw >> 2) & 63;                    // uniform
    float cc = 0.0f;
    #pragma unroll
    for (int s2 = 0; s2 < 16; ++s2) if (s2 == cell_slot) cc = vals[s2];
    const float cell = __shfl(cc, cell_lane, 64);

    const bool dead    = outside || (cell > 0.0f);
    const bool feeding = (cell == -1.0f);
    const bool spawn   = dead || feeding;

    const int pn_idx = dead ? (CH*S + CH)     : pn_raw;
    const int pc_idx = dead ? (CH*S + CH - 1) : (pcx * S + pcy);

    if (dead) {   // wave-uniform branch: reset pattern
        #pragma unroll
        for (int k = 0; k < 4; ++k)
            #pragma unroll
            for (int c = 0; c < 4; ++c) {
                const int j = k*256 + lane*4 + c;
                vals[k*4+c] = (j == CH*S + CH - 1) ? 2.0f
                            : ((j == CH*S + CH - 2) || (j == CH*S + CH)) ? 1.0f
                            : 0.0f;
            }
    }

    // ---- free counts: 4 per-quarter counts packed in one u64 (16b fields) ----
    int cnt0, cnt1, cnt2, cnt3;
    unsigned long long pack = 0ull;
    {
        int tmp[4];
        #pragma unroll
        for (int k = 0; k < 4; ++k) {
            int ck = 0;
            #pragma unroll
            for (int c = 0; c < 4; ++c) ck += (vals[k*4+c] == 0.0f) ? 1 : 0;
            tmp[k] = ck;
            pack |= (unsigned long long)ck << (16*k);
        }
        cnt0 = tmp[0]; cnt1 = tmp[1]; cnt2 = tmp[2]; cnt3 = tmp[3];
    }

    // inclusive scan over lanes (flat order within each quarter is lane-major)
    unsigned long long incl = pack;
    #pragma unroll
    for (int off = 1; off < 64; off <<= 1) {
        unsigned long long n = __shfl_up(incl, off, 64);
        if (lane >= off) incl += n;
    }
    const unsigned long long totp = __shfl(incl, 63, 64);
    const int t0 = (int)( totp        & 0xffff);
    const int t1 = (int)((totp >> 16) & 0xffff);
    const int t2 = (int)((totp >> 32) & 0xffff);
    const int t3 = (int)((totp >> 48) & 0xffff);
    const int total = t0 + t1 + t2 + t3;

    // food = index of (K+1)-th free cell in flat order, K = floor(ru*total)
    const float thresh = ru * (float)total;
    const int target = (int)thresh + 1;

    int foodloc = CELLS - 1;
    bool owns = false;
    {
        const int Q0 = 0, Q1 = t0, Q2 = t0 + t1, Q3 = t0 + t1 + t2;
        const int Qk[4]   = {Q0, Q1, Q2, Q3};
        const int cntk[4] = {cnt0, cnt1, cnt2, cnt3};
        #pragma unroll
        for (int k = 0; k < 4; ++k) {
            const int inclk = (int)((incl >> (16*k)) & 0xffff);
            const int ex = Qk[k] + inclk - cntk[k];      // global excl prefix
            if (ex < target && target <= ex + cntk[k]) {
                int acc = 0;
                const int r = target - ex;               // 1..4
                #pragma unroll
                for (int c = 0; c < 4; ++c) {
                    acc += (vals[k*4+c] == 0.0f) ? 1 : 0;
                    if (acc == r) { foodloc = k*256 + lane*4 + c; acc = -1000; }
                }
                owns = true;
            }
        }
    }
    const unsigned long long omask = __ballot(owns);
    int food = CELLS - 1;
    if (omask) food = __shfl(foodloc, __ffsll(omask) - 1, 64);

    // ---- head value: post-food, post-dec value at pos_cur, +1 ----
    const int pc_slot = ((pc_idx >> 8) << 2) | (pc_idx & 3);     // uniform
    const int pc_lane = (pc_idx >> 2) & 63;                      // uniform
    float pcc = 0.0f;
    #pragma unroll
    for (int s2 = 0; s2 < 16; ++s2) if (s2 == pc_slot) pcc = vals[s2];
    float vc = __shfl(pcc, pc_lane, 64);
    if (spawn && pc_idx == food) vc = -1.0f;
    if (vc > 0.0f && !feeding) vc -= 1.0f;
    const float head_val = vc + 1.0f;

    // ---- per-cell output: food set -> decrement -> head write ----
    #pragma unroll
    for (int k = 0; k < 4; ++k)
        #pragma unroll
        for (int c = 0; c < 4; ++c) {
            const int j = k*256 + lane*4 + c;
            float val = vals[k*4+c];
            if (spawn && j == food) val = -1.0f;
            if (val > 0.0f && !feeding) val -= 1.0f;
            if (j == pn_idx) val = head_val;
            vals[k*4+c] = val;
        }

    // ---- coalesced stores: 4 instructions, each a contiguous 1KB ----
    float4* op = reinterpret_cast<float4*>(out + gbase);
    op[lane]       = make_float4(vals[0],  vals[1],  vals[2],  vals[3]);
    op[lane + 64]  = make_float4(vals[4],  vals[5],  vals[6],  vals[7]);
    op[lane + 128] = make_float4(vals[8],  vals[9],  vals[10], vals[11]);
    op[lane + 192] = make_float4(vals[12], vals[13], vals[14], vals[15]);
}

extern "C" void kernel_launch(void* const* d_in, const int* in_sizes, int n_in,
                              void* d_out, int out_size, void* d_ws, size_t ws_size,
                              hipStream_t stream) {
    const float* state    = (const float*)d_in[0];
    const int*   pos_prev = (const int*)  d_in[1];
    const int*   pos_cur  = (const int*)  d_in[2];
    const int*   action   = (const int*)  d_in[3];
    const float* rand_u   = (const float*)d_in[4];
    float* outp = (float*)d_out;
    const int G = in_sizes[3];   // action has one entry per game
    snake_kernel<<<G / GPB, 256, 0, stream>>>(state, pos_prev, pos_cur, action, rand_u, outp);
}

// Round 4
// 87.395 us; speedup vs baseline: 1.3636x; 1.1321x over previous
//
#include <hip/hip_runtime.h>

// TensorSnake step: G games, 32x32 board, fp32 state in {-1,0,1..len}.
// One WAVE (64 lanes) per game, 4 games per 256-thread block.
// INTERLEAVED ownership: lane i owns cells j = k*256 + 4i + c (k,c in 0..3),
// so each 16B load/store instruction is a contiguous 1KB segment (perfect
// coalescing). Flat-order free-cell scan via ONE u64 shfl_up scan with four
// packed 16-bit per-quarter counts. No LDS, no barriers, no global gather.
// Bulk streams are single-use -> non-temporal loads/stores (nt cache bypass).

constexpr int S = 32;
constexpr int CELLS = S * S;   // 1024
constexpr int CH = S / 2;      // 16
constexpr int GPB = 4;         // games (waves) per block

typedef float f4 __attribute__((ext_vector_type(4)));

__global__ __launch_bounds__(256) void snake_kernel(
    const float* __restrict__ state,
    const int*   __restrict__ pos_prev,
    const int*   __restrict__ pos_cur,
    const int*   __restrict__ action,
    const float* __restrict__ rand_u,
    float*       __restrict__ out)
{
    const int lane = threadIdx.x & 63;
    const int g    = blockIdx.x * GPB + (threadIdx.x >> 6);
    const size_t gbase = (size_t)g * CELLS;

    // ---- per-game scalars first (they head the dependency chain) ----
    const int ppx = pos_prev[2*g],   ppy = pos_prev[2*g+1];
    const int pcx = pos_cur[2*g],    pcy = pos_cur[2*g+1];
    const int act = action[g];
    const float ru = rand_u[g];

    // ---- coalesced bulk load: 4 instructions, each a contiguous 1KB, NT ----
    const f4* sp = reinterpret_cast<const f4*>(state + gbase);
    const f4 v0 = __builtin_nontemporal_load(sp + lane);
    const f4 v1 = __builtin_nontemporal_load(sp + lane + 64);
    const f4 v2 = __builtin_nontemporal_load(sp + lane + 128);
    const f4 v3 = __builtin_nontemporal_load(sp + lane + 192);

    int dx = pcx - ppx, dy = pcy - ppy;
    int ndx, ndy;
    if (act == 0)      { ndx = -dy; ndy =  dx; }   // left
    else if (act == 2) { ndx =  dy; ndy = -dx; }   // right
    else               { ndx =  dx; ndy =  dy; }   // straight
    int pnx = pcx + ndx, pny = pcy + ndy;
    const bool outside = (pnx < 0) || (pnx >= S) || (pny < 0) || (pny >= S);
    pnx = min(max(pnx, 0), S - 1);
    pny = min(max(pny, 0), S - 1);
    const int pn_raw = pnx * S + pny;   // clipped pn, flat index (uniform)

    // ---- board in registers; slot s = k*4+c holds cell j = k*256+4*lane+c ----
    float vals[16];
    vals[0]=v0.x; vals[1]=v0.y; vals[2]=v0.z; vals[3]=v0.w;
    vals[4]=v1.x; vals[5]=v1.y; vals[6]=v1.z; vals[7]=v1.w;
    vals[8]=v2.x; vals[9]=v2.y; vals[10]=v2.z; vals[11]=v2.w;
    vals[12]=v3.x; vals[13]=v3.y; vals[14]=v3.z; vals[15]=v3.w;

    // ---- head-cell probe from registers (no global gather) ----
    const int cell_slot = ((pn_raw >> 8) << 2) | (pn_raw & 3);   // uniform
    const int cell_lane = (pn_raw >> 2) & 63;                    // uniform
    float cc = 0.0f;
    #pragma unroll
    for (int s2 = 0; s2 < 16; ++s2) if (s2 == cell_slot) cc = vals[s2];
    const float cell = __shfl(cc, cell_lane, 64);

    const bool dead    = outside || (cell > 0.0f);
    const bool feeding = (cell == -1.0f);
    const bool spawn   = dead || feeding;

    const int pn_idx = dead ? (CH*S + CH)     : pn_raw;
    const int pc_idx = dead ? (CH*S + CH - 1) : (pcx * S + pcy);

    if (dead) {   // wave-uniform branch: reset pattern
        #pragma unroll
        for (int k = 0; k < 4; ++k)
            #pragma unroll
            for (int c = 0; c < 4; ++c) {
                const int j = k*256 + lane*4 + c;
                vals[k*4+c] = (j == CH*S + CH - 1) ? 2.0f
                            : ((j == CH*S + CH - 2) || (j == CH*S + CH)) ? 1.0f
                            : 0.0f;
            }
    }

    // ---- free counts: 4 per-quarter counts packed in one u64 (16b fields) ----
    int cnt0, cnt1, cnt2, cnt3;
    unsigned long long pack = 0ull;
    {
        int tmp[4];
        #pragma unroll
        for (int k = 0; k < 4; ++k) {
            int ck = 0;
            #pragma unroll
            for (int c = 0; c < 4; ++c) ck += (vals[k*4+c] == 0.0f) ? 1 : 0;
            tmp[k] = ck;
            pack |= (unsigned long long)ck << (16*k);
        }
        cnt0 = tmp[0]; cnt1 = tmp[1]; cnt2 = tmp[2]; cnt3 = tmp[3];
    }

    // inclusive scan over lanes (flat order within each quarter is lane-major)
    unsigned long long incl = pack;
    #pragma unroll
    for (int off = 1; off < 64; off <<= 1) {
        unsigned long long n = __shfl_up(incl, off, 64);
        if (lane >= off) incl += n;
    }
    const unsigned long long totp = __shfl(incl, 63, 64);
    const int t0 = (int)( totp        & 0xffff);
    const int t1 = (int)((totp >> 16) & 0xffff);
    const int t2 = (int)((totp >> 32) & 0xffff);
    const int t3 = (int)((totp >> 48) & 0xffff);
    const int total = t0 + t1 + t2 + t3;

    // food = index of (K+1)-th free cell in flat order, K = floor(ru*total)
    const float thresh = ru * (float)total;
    const int target = (int)thresh + 1;

    int foodloc = CELLS - 1;
    bool owns = false;
    {
        const int Qk[4]   = {0, t0, t0 + t1, t0 + t1 + t2};
        const int cntk[4] = {cnt0, cnt1, cnt2, cnt3};
        #pragma unroll
        for (int k = 0; k < 4; ++k) {
            const int inclk = (int)((incl >> (16*k)) & 0xffff);
            const int ex = Qk[k] + inclk - cntk[k];      // global excl prefix
            if (ex < target && target <= ex + cntk[k]) {
                int acc = 0;
                const int r = target - ex;               // 1..4
                #pragma unroll
                for (int c = 0; c < 4; ++c) {
                    acc += (vals[k*4+c] == 0.0f) ? 1 : 0;
                    if (acc == r) { foodloc = k*256 + lane*4 + c; acc = -1000; }
                }
                owns = true;
            }
        }
    }
    const unsigned long long omask = __ballot(owns);
    int food = CELLS - 1;
    if (omask) food = __shfl(foodloc, __ffsll(omask) - 1, 64);

    // ---- head value: post-food, post-dec value at pos_cur, +1 ----
    const int pc_slot = ((pc_idx >> 8) << 2) | (pc_idx & 3);     // uniform
    const int pc_lane = (pc_idx >> 2) & 63;                      // uniform
    float pcc = 0.0f;
    #pragma unroll
    for (int s2 = 0; s2 < 16; ++s2) if (s2 == pc_slot) pcc = vals[s2];
    float vc = __shfl(pcc, pc_lane, 64);
    if (spawn && pc_idx == food) vc = -1.0f;
    if (vc > 0.0f && !feeding) vc -= 1.0f;
    const float head_val = vc + 1.0f;

    // ---- per-cell output: food set -> decrement -> head write ----
    #pragma unroll
    for (int k = 0; k < 4; ++k)
        #pragma unroll
        for (int c = 0; c < 4; ++c) {
            const int j = k*256 + lane*4 + c;
            float val = vals[k*4+c];
            if (spawn && j == food) val = -1.0f;
            if (val > 0.0f && !feeding) val -= 1.0f;
            if (j == pn_idx) val = head_val;
            vals[k*4+c] = val;
        }

    // ---- coalesced NT stores: 4 instructions, each a contiguous 1KB ----
    f4* op = reinterpret_cast<f4*>(out + gbase);
    f4 o0 = {vals[0],  vals[1],  vals[2],  vals[3]};
    f4 o1 = {vals[4],  vals[5],  vals[6],  vals[7]};
    f4 o2 = {vals[8],  vals[9],  vals[10], vals[11]};
    f4 o3 = {vals[12], vals[13], vals[14], vals[15]};
    __builtin_nontemporal_store(o0, op + lane);
    __builtin_nontemporal_store(o1, op + lane + 64);
    __builtin_nontemporal_store(o2, op + lane + 128);
    __builtin_nontemporal_store(o3, op + lane + 192);
}

extern "C" void kernel_launch(void* const* d_in, const int* in_sizes, int n_in,
                              void* d_out, int out_size, void* d_ws, size_t ws_size,
                              hipStream_t stream) {
    const float* state    = (const float*)d_in[0];
    const int*   pos_prev = (const int*)  d_in[1];
    const int*   pos_cur  = (const int*)  d_in[2];
    const int*   action   = (const int*)  d_in[3];
    const float* rand_u   = (const float*)d_in[4];
    float* outp = (float*)d_out;
    const int G = in_sizes[3];   // action has one entry per game
    snake_kernel<<<G / GPB, 256, 0, stream>>>(state, pos_prev, pos_cur, action, rand_u, outp);
}